// Round 9
// baseline (725.387 us; speedup 1.0000x reference)
//
#include <hip/hip_runtime.h>

// SuperpixelPooling: per-(batch, superpixel) mean of 64-dim feature vectors.
// feat[8,512,512,64] f32, labels[8,512,512] i32 in [0,256) -> out[8,256,64] f32.
//
// Round-8. r7 post-mortem: three structurally different kernels (r2 ballot-
// scan, r6 queue+gather, r7 deepened queue+gather) all land at ~350-375us of
// controllable time (total minus the harness's 333us 2GiB re-poison fill).
// Common factor: every pixel's features arrive as a 256B wave-GATHER from
// HBM/L3 with a dependent LDS-rmw consumer. Models say the LDS side is cheap;
// the invariant ~350us says the gather path is the wall.
//
// r8 eliminates the gather class entirely:
//   - STREAM: per round, 8 waves cooperatively stage 128 pixels (32 KB) of
//     features into an LDS tile with perfectly coalesced float4 loads
//     (1 KB/wave-instr; the pattern the 6.4TB/s fill kernel proves out).
//     Reg-buffered: round r+1's loads issue before round r's scatter, HBM
//     latency hides under it. Features read once, sequentially.
//   - CLAIM: wave w owns segments [32w,32w+32). 2 ballots over the tile's
//     128 labels; mbcnt rank-compaction packs (label<<8|px) into a per-wave
//     LDS queue (padded to x4 with per-wave dummy rows). Counts via divergent
//     ds-atomic at claim time (~16 lanes, distinct rows; cheap per r7).
//   - SCATTER: per queue entry, full-wave b32 LDS->LDS rmw:
//     hist[row*64+lane] += tile[px*64+lane]. Strictly sequential per pixel
//     (same-wave LDS ordering => dup-label safe); rows wave-exclusive (no
//     cross-wave race); bank-perfect (64 consecutive dwords = 2/bank).
//   - 32 rounds x 2 barriers; flush per-block partials (plain float4 stores)
//     + counts to ws; reduce_kernel (unchanged from r7) sums 64 slabs and
//     divides. LDS ~105 KB -> 1 block/CU, 8 waves.
//
// Pre-committed read: total ~460-510us => gather was the wall, tune stream
// next; total ~690us => ~350us is not kernel time, pivot to launch structure.

#define NBATCH 8
#define NSEG 256
#define NCH 64
#define PPB (512 * 512)                        // 262144 pixels per batch
#define BPB 64                                 // blocks per batch
#define PIX_PER_BLOCK 4096
#define NWAVE 8
#define TILE_PX 128                            // pixels staged per round
#define ROUNDS (PIX_PER_BLOCK / TILE_PX)       // 32
#define PXW (TILE_PX / NWAVE)                  // 16 px staged per wave
#define QMAX 132                               // 128 worst case + 3 pad
#define NROWS (NSEG + NWAVE)                   // 256 real + 8 dummy rows

__global__ __launch_bounds__(512, 2) void pool_kernel(const float* __restrict__ feat,
                                                      const int* __restrict__ sp,
                                                      float* __restrict__ pspart,
                                                      unsigned* __restrict__ pscnt) {
    __shared__ float hist[NROWS * NCH];        // 67.6 KB, rows wave-exclusive
    __shared__ float tile[TILE_PX * NCH];      // 32 KB staged features
    __shared__ int qd[NWAVE][QMAX];            // 4.2 KB
    __shared__ unsigned cnt[NROWS];            // 1.06 KB  -> ~105 KB, 1 blk/CU

    const int b = blockIdx.x >> 6;
    const int slab = blockIdx.x & 63;
    const int tid = threadIdx.x;
    const int lane = tid & 63;
    const int wave = tid >> 6;

    for (int i = tid; i < (NROWS * NCH) / 4; i += 512)
        ((float4*)hist)[i] = make_float4(0.f, 0.f, 0.f, 0.f);
    if (tid < NROWS) cnt[tid] = 0u;

    const int gpix0 = slab * PIX_PER_BLOCK;    // batch-local pixel offset
    const float4* fbase = (const float4*)(feat + ((size_t)b * PPB + gpix0) * NCH);
    const int2* lp2 = (const int2*)(sp + (size_t)b * PPB + gpix0);

    const int dummy_e = (NSEG + wave) << 8;    // dummy row, tile px 0
    int* q = qd[wave];
    float4* t4 = (float4*)tile;
    const int wslice = wave * PXW * 16;        // wave's float4 offset in tile

    // stage: wave's 16 px = 4 KB = 4 coalesced float4 loads per lane
    float4 buf0, buf1, buf2, buf3;
#define STAGE_LOAD(R)                                                         \
    {   const int fb_ = ((R) * TILE_PX) * 16 + wslice;                        \
        buf0 = fbase[fb_ + lane];        buf1 = fbase[fb_ + 64 + lane];       \
        buf2 = fbase[fb_ + 128 + lane];  buf3 = fbase[fb_ + 192 + lane];  }
#define STAGE_WRITE()                                                         \
    {   t4[wslice + lane] = buf0;        t4[wslice + 64 + lane] = buf1;       \
        t4[wslice + 128 + lane] = buf2;  t4[wslice + 192 + lane] = buf3;  }

    STAGE_LOAD(0);
    STAGE_WRITE();                              // hist init + tile ready after
    for (int r = 0; r < ROUNDS; ++r) {
        if (r + 1 < ROUNDS) STAGE_LOAD(r + 1);  // issue early; consumed at end
        __syncthreads();                        // tile (and round-0 hist init) visible

        // ---- claim: 128 labels, 2 ballots, rank-compacted into q ----
        const int2 L = lp2[r * 64 + lane];
        int qn = 0;
#define PUSH(SV, PX)                                                          \
        {                                                                     \
            const int s_ = (SV);                                              \
            const bool own_ = ((s_ >> 5) == wave);                            \
            const unsigned long long m_ = __ballot(own_);                     \
            if (own_) {                                                       \
                const int r_ = __builtin_amdgcn_mbcnt_hi(                     \
                    (unsigned)(m_ >> 32),                                     \
                    __builtin_amdgcn_mbcnt_lo((unsigned)m_, 0));              \
                q[qn + r_] = (s_ << 8) | (PX);                                \
                atomicAdd(&cnt[s_], 1u);                                      \
            }                                                                 \
            qn += __builtin_popcountll(m_);                                   \
        }
        PUSH(L.x, 2 * lane)
        PUSH(L.y, 2 * lane + 1)
#undef PUSH
        const int npad = (4 - (qn & 3)) & 3;   // pad to x4 (dummy rows)
        if (lane < npad) q[qn + lane] = dummy_e;
        qn += npad;

        // ---- scatter: per-pixel full-wave b32 LDS->LDS rmw ----
        const int ng = qn >> 2;
        for (int g = 0; g < ng; ++g) {
            const int4 e = *(const int4*)&q[g * 4];       // uniform broadcast
            const float v0 = tile[(e.x & 255) * NCH + lane];  // independent reads,
            const float v1 = tile[(e.y & 255) * NCH + lane];  // issue together
            const float v2 = tile[(e.z & 255) * NCH + lane];
            const float v3 = tile[(e.w & 255) * NCH + lane];
            hist[(e.x >> 8) * NCH + lane] += v0;   // sequential rmw: in-order
            hist[(e.y >> 8) * NCH + lane] += v1;   // within wave, dup-safe
            hist[(e.z >> 8) * NCH + lane] += v2;
            hist[(e.w >> 8) * NCH + lane] += v3;
        }

        __syncthreads();                        // all waves done reading tile
        if (r + 1 < ROUNDS) STAGE_WRITE();      // overwrite tile for next round
    }
    __syncthreads();

    // flush per-block partials: plain coalesced float4 stores (no atomics)
    float4* wp = (float4*)(pspart + (size_t)blockIdx.x * (NSEG * NCH));
    const float4* hs = (const float4*)hist;     // first 256 rows contiguous
    for (int i = tid; i < (NSEG * NCH) / 4; i += 512) wp[i] = hs[i];
    if (tid < NSEG) pscnt[(size_t)blockIdx.x * NSEG + tid] = cnt[tid];
}

// One block (1 wave) per (batch, segment): sum 64 slab partials, divide.
__global__ __launch_bounds__(64) void reduce_kernel(const float* __restrict__ pspart,
                                                    const unsigned* __restrict__ pscnt,
                                                    float* __restrict__ out) {
    const int bs = blockIdx.x;                 // b * NSEG + seg
    const int bnum = bs >> 8;
    const int seg = bs & 255;
    const int lane = threadIdx.x;              // 64 = channel

    const float* base = pspart + ((size_t)bnum * BPB * NSEG + seg) * NCH + lane;
    float acc = 0.f;
#pragma unroll
    for (int s = 0; s < BPB; ++s)              // 64 independent 256B row reads
        acc += base[(size_t)s * NSEG * NCH];

    unsigned c = pscnt[((size_t)bnum * BPB + lane) * NSEG + seg];  // lane = slab
    for (int o = 32; o; o >>= 1) c += __shfl_xor(c, o);            // total everywhere

    out[(size_t)bs * NCH + lane] = acc / (float)(c > 0u ? c : 1u);
}

extern "C" void kernel_launch(void* const* d_in, const int* in_sizes, int n_in,
                              void* d_out, int out_size, void* d_ws, size_t ws_size,
                              hipStream_t stream) {
    const float* feat = (const float*)d_in[0];
    const int* sp = (const int*)d_in[1];
    float* out = (float*)d_out;
    float* pspart = (float*)d_ws;                               // 33.5 MB
    unsigned* pscnt = (unsigned*)((char*)d_ws + (size_t)NBATCH * BPB * NSEG * NCH * 4);
    (void)in_sizes; (void)n_in; (void)out_size; (void)ws_size;

    pool_kernel<<<NBATCH * BPB, 512, 0, stream>>>(feat, sp, pspart, pscnt);
    reduce_kernel<<<NBATCH * NSEG, 64, 0, stream>>>(pspart, pscnt, out);
}